// Round 16
// baseline (86.338 us; speedup 1.0000x reference)
//
#include <hip/hip_runtime.h>
#include <hip/hip_bf16.h>
#include <math.h>

// Problem constants
#define D       18
#define KCB     4096       // codebook entries
#define NROW    32768      // 8 * 64 * 64
#define RPB     64         // pixels per block = lanes per wave
#define NPT     4          // pixel tiles of 16
#define NWAVE   8          // waves per block; each owns 512 k (32 tiles of 16)
#define KTPW    32         // k-tiles per wave
#define NBLK    (NROW / RPB)   // 512 blocks

#define P100     144.26950408889634f   // 100 * log2(e)
#define SEED1    (-152.26950408889634f) // -(P100 + 8): keeps all t strictly < 0
#define LN2f     0.6931471805599453f
#define INVP100  0.006931471805599453f // 1/P100
#define DELTA    0.25f                 // recheck window: 2x key quant + split err

#define Q_OFF   0
#define IDX_OFF 589824               // 8*18*64*64
#define SCL_OFF 622592               // + 32768

// ws layout (floats):
//   [0..1]      E-sum (sum e*t2), commit-sum
//   [16..)      kvec (4096)
//   [8192..)    SP_ext tiled A-fragments (4096 k x 128B = 131072 floats)
//   [139264..)  per-block kvec partials (512 x 4096), exclusive rows, plain stores
#define WS_SCAL  0
#define WS_KVEC  16
#define WS_SPEXT 8192
#define WS_PART  139264
#define WS_END   (WS_PART + NBLK * KCB)

typedef __attribute__((ext_vector_type(8))) short bf16x8;
typedef __attribute__((ext_vector_type(4))) float f32x4;

__device__ __forceinline__ unsigned int f2bf(float f, float& residual)
{
    __hip_bfloat16 b = __float2bfloat16(f);       // RNE
    residual = f - __bfloat162float(b);
    union { __hip_bfloat16 b; unsigned short u; } cv;
    cv.b = b;
    return (unsigned int)cv.u;
}

// Precompute codebook fragments, MFMA-tile-contiguous (verified r8-r15).
// SP ext row (64 bf16): [h0..h17 | h0..h17 | l0..l17 | 0 x10]
__global__ __launch_bounds__(256)
void hs_prep(const float* __restrict__ sp, unsigned int* __restrict__ spx)
{
    const int k  = blockIdx.x * 256 + threadIdx.x;   // 16 blocks x 256 = 4096
    const int kt = k >> 4, r = k & 15;
    unsigned int hu[18], lu[18];
#pragma unroll
    for (int j = 0; j < D; ++j) {
        float res, res2;
        hu[j] = f2bf(sp[k * D + j], res);
        lu[j] = f2bf(res, res2);
    }
    unsigned int w[32];
#pragma unroll
    for (int i = 0; i < 9; ++i) {
        unsigned int hwv = hu[2 * i] | (hu[2 * i + 1] << 16);
        unsigned int lwv = lu[2 * i] | (lu[2 * i + 1] << 16);
        w[i] = hwv; w[9 + i] = hwv; w[18 + i] = lwv;
    }
#pragma unroll
    for (int i = 27; i < 32; ++i) w[i] = 0;
#pragma unroll
    for (int g = 0; g < 4; ++g) {
        unsigned int* dst = spx + (size_t)kt * 512 + (g * 16 + r) * 8;
        *(uint4*)(dst)     = make_uint4(w[g*4], w[g*4+1], w[g*4+2], w[g*4+3]);
        *(uint4*)(dst + 4) = make_uint4(w[16+g*4], w[16+g*4+1], w[16+g*4+2], w[16+g*4+3]);
    }
}

__global__ __launch_bounds__(512, 4)
void hs_main(const float* __restrict__ x, const float* __restrict__ sp,
             float* __restrict__ out_q, float* __restrict__ out_idx,
             float* __restrict__ ws_scal, const unsigned int* __restrict__ spx,
             float* __restrict__ ws_part, float* __restrict__ ws_kvec)
{
    __shared__ unsigned int xe[RPB][36];     // pixel ext rows [h|l|h|0], 144B stride
    __shared__ float        xsl_lds[RPB][20];// exact fp32 P100-scaled rows
    __shared__ float        zw[NWAVE][RPB];
    __shared__ unsigned int k1w[NWAVE][RPB], k2w[NWAVE][RPB];
    __shared__ float        An_lds[RPB];     // -(P100 + 8 + log2 Z)
    __shared__ float        entw[NWAVE];

    const int tid = threadIdx.x;
    const int l   = tid & 63;                                  // lane
    const int wu  = __builtin_amdgcn_readfirstlane(tid >> 6);  // wave id
    const int col = l & 15, g = l >> 4;
    const int kof = g * 4;
    const int row = blockIdx.x * RPB + l;
    const int b   = row >> 12;
    const int p   = row & 4095;

    // ---- wave 0: load+normalize x rows (P100-scaled); build xe + xsl ----
    if (wu == 0) {
        float xs[D];
        float ssq = 0.f;
#pragma unroll
        for (int j = 0; j < D; ++j) {
            float v = x[(b * D + j) * 4096 + p];
            xs[j] = v;
            ssq += v * v;
        }
        const float sf = (1.0f / sqrtf(ssq)) * P100;
#pragma unroll
        for (int j = 0; j < D; ++j) xs[j] *= sf;
#pragma unroll
        for (int j = 0; j < D; ++j) xsl_lds[l][j] = xs[j];

        unsigned int hu[18], lu[18];
#pragma unroll
        for (int j = 0; j < D; ++j) {
            float res, res2;
            hu[j] = f2bf(xs[j], res);
            lu[j] = f2bf(res, res2);
        }
#pragma unroll
        for (int i = 0; i < 9; ++i) {
            unsigned int hwv = hu[2 * i] | (hu[2 * i + 1] << 16);
            unsigned int lwv = lu[2 * i] | (lu[2 * i + 1] << 16);
            xe[l][i] = hwv; xe[l][9 + i] = lwv; xe[l][18 + i] = hwv;
        }
#pragma unroll
        for (int i = 27; i < 32; ++i) xe[l][i] = 0;
    }
    __syncthreads();

    // ---- loop-invariant X fragments (shared by both sweeps) ----
    union { uint4 u; bf16x8 v; } cv;
    bf16x8 fxlo[NPT], fxhi[NPT];
#pragma unroll
    for (int pt = 0; pt < NPT; ++pt) {
        cv.u = *(const uint4*)&xe[pt * 16 + col][g * 4];      fxlo[pt] = cv.v;
        cv.u = *(const uint4*)&xe[pt * 16 + col][16 + g * 4]; fxhi[pt] = cv.v;
    }

    // ---- sweep 1 (MFMA): t = P100*s - (P100+8); Z + packed top-2 (min-keys),
    //      software-pipelined spx prefetch ----
    float Zp[NPT] = {0.f, 0.f, 0.f, 0.f};
    unsigned int k1p[NPT] = {0xFFFFFFFFu, 0xFFFFFFFFu, 0xFFFFFFFFu, 0xFFFFFFFFu};
    unsigned int k2p[NPT] = {0xFFFFFFFFu, 0xFFFFFFFFu, 0xFFFFFFFFu, 0xFFFFFFFFu};
    const unsigned int MASKV = 0xFFFFF000u;
    const int kt0 = wu * KTPW;
    const unsigned int* spw = spx + (size_t)kt0 * 512 + l * 8;  // wave slice base

    uint4 na = *(const uint4*)(spw);
    uint4 nb = *(const uint4*)(spw + 4);

#pragma unroll 2
    for (int kt = 0; kt < KTPW; ++kt) {
        cv.u = na; const bf16x8 alo = cv.v;
        cv.u = nb; const bf16x8 ahi = cv.v;
        const int ktn = (kt + 1 < KTPW) ? kt + 1 : kt;
        na = *(const uint4*)(spw + (size_t)ktn * 512);
        nb = *(const uint4*)(spw + (size_t)ktn * 512 + 4);

        const unsigned int kb = (unsigned int)(((kt0 + kt) << 4) + kof);
#pragma unroll
        for (int pt = 0; pt < NPT; ++pt) {
            f32x4 c = {SEED1, SEED1, SEED1, SEED1};
            c = __builtin_amdgcn_mfma_f32_16x16x32_bf16(alo, fxlo[pt], c, 0, 0, 0);
            c = __builtin_amdgcn_mfma_f32_16x16x32_bf16(ahi, fxhi[pt], c, 0, 0, 0);
#pragma unroll
            for (int r = 0; r < 4; ++r) {
                const float t = c[r];
                const unsigned int key =
                    (__float_as_uint(t) & MASKV) | (kb + (unsigned)r);
                k2p[pt] = min(k2p[pt], max(k1p[pt], key));   // uses old k1p
                k1p[pt] = min(k1p[pt], key);
                Zp[pt] += __builtin_amdgcn_exp2f(t);
            }
        }
    }

    // merge across the 4 g-groups (lanes col, col+16, col+32, col+48)
#pragma unroll
    for (int off = 16; off < 64; off <<= 1) {
#pragma unroll
        for (int pt = 0; pt < NPT; ++pt) {
            Zp[pt] += __shfl_xor(Zp[pt], off);
            unsigned int ok1 = (unsigned int)__shfl_xor((int)k1p[pt], off);
            unsigned int ok2 = (unsigned int)__shfl_xor((int)k2p[pt], off);
            k2p[pt] = min(min(k2p[pt], ok2), max(k1p[pt], ok1));
            k1p[pt] = min(k1p[pt], ok1);
        }
    }
    if (g == 0) {
#pragma unroll
        for (int pt = 0; pt < NPT; ++pt) {
            const int px = pt * 16 + col;
            zw[wu][px] = Zp[pt];
            k1w[wu][px] = k1p[pt];
            k2w[wu][px] = k2p[pt];
        }
    }
    __syncthreads();

    // ---- wave 0: cross-wave merge + recheck + epilogue ----
    if (wu == 0) {
        float Zt = zw[0][l];
        unsigned int k1 = k1w[0][l], k2 = k2w[0][l];
#pragma unroll
        for (int s = 1; s < NWAVE; ++s) {
            Zt += zw[s][l];
            unsigned int ok1 = k1w[s][l], ok2 = k2w[s][l];
            k2 = min(min(k2, ok2), max(k1, ok1));
            k1 = min(k1, ok1);
        }
        const float l2Z = log2f(Zt);
        An_lds[l] = -(P100 + 8.0f + l2Z);

        float xsl[D];
#pragma unroll
        for (int j = 0; j < D; ++j) xsl[j] = xsl_lds[l][j];

        int i1 = (int)(k1 & 0xFFFu);
        int i2 = (int)(k2 & 0xFFFu);
        const float tq1 = __uint_as_float(k1 & MASKV);
        const float tq2 = __uint_as_float(k2 & MASKV);
        int it = i1;
        if (tq1 - tq2 < DELTA) {   // exact fp32 recheck of the two candidates
            const float2* r1 = (const float2*)(sp + i1 * D);
            const float2* r2 = (const float2*)(sp + i2 * D);
            float d1 = 0.f, d2 = 0.f;
#pragma unroll
            for (int j = 0; j < 9; ++j) {
                d1 = fmaf(xsl[2 * j], r1[j].x, d1);
                d1 = fmaf(xsl[2 * j + 1], r1[j].y, d1);
                d2 = fmaf(xsl[2 * j], r2[j].x, d2);
                d2 = fmaf(xsl[2 * j + 1], r2[j].y, d2);
            }
            if (d2 > d1 || (d2 == d1 && i2 < i1)) it = i2;
        }
        out_idx[row] = (float)it;

        // gather chosen codeword (exact fp32); write q; commitment partial
        float2 gq[9];
        const float2* gr = (const float2*)(sp + it * D);
#pragma unroll
        for (int j = 0; j < 9; ++j) gq[j] = gr[j];
        float cp = 0.f;
#pragma unroll
        for (int j = 0; j < 9; ++j) {
            float qx = gq[j].x, qy = gq[j].y;
            float dx = fmaf(xsl[2 * j],     INVP100, -qx);
            float dy = fmaf(xsl[2 * j + 1], INVP100, -qy);
            cp = fmaf(dx, dx, cp);
            cp = fmaf(dy, dy, cp);
            out_q[(b * D + 2 * j)     * 4096 + p] = qx;
            out_q[(b * D + 2 * j + 1) * 4096 + p] = qy;
        }

        float v2 = cp;
#pragma unroll
        for (int off = 1; off < 64; off <<= 1) v2 += __shfl_xor(v2, off);
        if (l == 0) atomicAdd(&ws_scal[1], v2);
    }
    __syncthreads();   // publish An_lds

    // ---- sweep 2 (MFMA, roles swapped): kvec + deferred entropy,
    //      software-pipelined spx prefetch ----
    float4 an4[NPT];
#pragma unroll
    for (int pt = 0; pt < NPT; ++pt)
        an4[pt] = *(const float4*)&An_lds[pt * 16 + kof];

    float entacc = 0.f;
    float* pdst = ws_part ? ws_part + (size_t)blockIdx.x * KCB : nullptr;

    na = *(const uint4*)(spw);
    nb = *(const uint4*)(spw + 4);

#pragma unroll 2
    for (int kt = 0; kt < KTPW; ++kt) {
        cv.u = na; const bf16x8 alo = cv.v;
        cv.u = nb; const bf16x8 ahi = cv.v;
        const int ktn = (kt + 1 < KTPW) ? kt + 1 : kt;
        na = *(const uint4*)(spw + (size_t)ktn * 512);
        nb = *(const uint4*)(spw + (size_t)ktn * 512 + 4);

        float ksum = 0.f;
#pragma unroll
        for (int pt = 0; pt < NPT; ++pt) {
            f32x4 c = {an4[pt].x, an4[pt].y, an4[pt].z, an4[pt].w};
            c = __builtin_amdgcn_mfma_f32_16x16x32_bf16(fxlo[pt], alo, c, 0, 0, 0);
            c = __builtin_amdgcn_mfma_f32_16x16x32_bf16(fxhi[pt], ahi, c, 0, 0, 0);
#pragma unroll
            for (int r = 0; r < 4; ++r) {
                const float t2 = c[r];
                const float e = __builtin_amdgcn_exp2f(t2);
                ksum += e;
                entacc = fmaf(e, t2, entacc);
            }
        }
        ksum += __shfl_xor(ksum, 16);
        ksum += __shfl_xor(ksum, 32);
        if (g == 0) {
            const int kk = (kt0 + kt) * 16 + col;
            if (pdst) pdst[kk] = ksum;
            else      atomicAdd(&ws_kvec[kk], ksum);
        }
    }

    // block-reduce deferred-entropy partials, one atomic per block
#pragma unroll
    for (int off = 1; off < 64; off <<= 1) entacc += __shfl_xor(entacc, off);
    if (l == 0) entw[wu] = entacc;
    __syncthreads();
    if (tid == 0) {
        float e = 0.f;
#pragma unroll
        for (int s = 0; s < NWAVE; ++s) e += entw[s];
        atomicAdd(&ws_scal[0], e);
    }
}

// Reduce NBLK x KCB partials into kvec (verified r5+).
__global__ void hs_reduce(const float* __restrict__ part, float* __restrict__ kvec)
{
    const int kb = blockIdx.x & 15;
    const int sb = blockIdx.x >> 4;
    const int k  = kb * 256 + threadIdx.x;
    const float* pp = part + (size_t)sb * 32 * KCB + k;
    float s = 0.f;
#pragma unroll 8
    for (int bb = 0; bb < 32; ++bb) s += pp[bb * KCB];
    atomicAdd(&kvec[k], s);
}

__global__ void hs_final(const float* __restrict__ ws_kvec,
                         const float* __restrict__ ws_scal,
                         float* __restrict__ out)
{
    __shared__ float red[4];
    const int tid = threadIdx.x;
    float local = 0.f;
    for (int k = tid; k < KCB; k += 256) {
        float a = ws_kvec[k] * (1.0f / 32768.0f);
        local += a * (log2f(a + 1e-15f) * LN2f);
    }
#pragma unroll
    for (int off = 1; off < 64; off <<= 1) local += __shfl_xor(local, off);
    if ((tid & 63) == 0) red[tid >> 6] = local;
    __syncthreads();
    if (tid == 0) {
        float mean_entro = -(red[0] + red[1] + red[2] + red[3]);
        float entro_mean = -LN2f * ws_scal[0] * (1.0f / 32768.0f);
        float commit     = ws_scal[1] * (1.0f / (32768.0f * 18.0f));
        out[SCL_OFF + 0] = entro_mean;
        out[SCL_OFF + 1] = mean_entro;
        out[SCL_OFF + 2] = entro_mean - mean_entro;
        out[SCL_OFF + 3] = commit;
    }
}

extern "C" void kernel_launch(void* const* d_in, const int* in_sizes, int n_in,
                              void* d_out, int out_size, void* d_ws, size_t ws_size,
                              hipStream_t stream)
{
    const float* x  = (const float*)d_in[0];
    const float* sp = (const float*)d_in[1];
    float* out = (float*)d_out;
    float* ws  = (float*)d_ws;

    const bool partials = ws_size >= (size_t)WS_END * sizeof(float);

    hipMemsetAsync(ws, 0, (WS_KVEC + KCB) * sizeof(float), stream);

    hs_prep<<<16, 256, 0, stream>>>(sp, (unsigned int*)(ws + WS_SPEXT));
    hs_main<<<NBLK, 512, 0, stream>>>(x, sp, out + Q_OFF, out + IDX_OFF,
                                      ws + WS_SCAL,
                                      (const unsigned int*)(ws + WS_SPEXT),
                                      partials ? ws + WS_PART : nullptr,
                                      ws + WS_KVEC);
    if (partials)
        hs_reduce<<<256, 256, 0, stream>>>(ws + WS_PART, ws + WS_KVEC);
    hs_final<<<1, 256, 0, stream>>>(ws + WS_KVEC, ws + WS_SCAL, out);
}

// Round 17
// 80.815 us; speedup vs baseline: 1.0683x; 1.0683x over previous
//
#include <hip/hip_runtime.h>
#include <hip/hip_bf16.h>
#include <math.h>

// Problem constants
#define D       18
#define KCB     4096       // codebook entries
#define NROW    32768      // 8 * 64 * 64
#define RPB     64         // pixels per block = lanes per wave
#define NPT     4          // pixel tiles of 16
#define NWAVE   8          // waves per block; each owns 512 k (32 tiles of 16)
#define KTPW    32         // k-tiles per wave
#define NBLK    (NROW / RPB)   // 512 blocks

#define P100     144.26950408889634f   // 100 * log2(e)
#define SEED1    (-152.26950408889634f) // -(P100 + 8): keeps all t strictly < 0
#define LN2f     0.6931471805599453f
#define INVP100  0.006931471805599453f // 1/P100
#define DELTA    0.25f                 // recheck window: 2x key quant + split err

#define Q_OFF   0
#define IDX_OFF 589824               // 8*18*64*64
#define SCL_OFF 622592               // + 32768

// ws layout (floats):
//   [0..1]      E-sum (sum e*t2), commit-sum
//   [16..)      kvec (4096)
//   [8192..)    SP_ext tiled A-fragments (4096 k x 128B = 131072 floats)
//   [139264..)  per-block kvec partials (512 x 4096)
#define WS_SCAL  0
#define WS_KVEC  16
#define WS_SPEXT 8192
#define WS_PART  139264
#define WS_END   (WS_PART + NBLK * KCB)

typedef __attribute__((ext_vector_type(8))) short bf16x8;
typedef __attribute__((ext_vector_type(4))) float f32x4;

__device__ __forceinline__ unsigned int f2bf(float f, float& residual)
{
    __hip_bfloat16 b = __float2bfloat16(f);       // RNE
    residual = f - __bfloat162float(b);
    union { __hip_bfloat16 b; unsigned short u; } cv;
    cv.b = b;
    return (unsigned int)cv.u;
}

// Precompute codebook fragments, MFMA-tile-contiguous (verified r8+).
// SP ext row (64 bf16): [h0..h17 | h0..h17 | l0..l17 | 0 x10]
__global__ __launch_bounds__(256)
void hs_prep(const float* __restrict__ sp, unsigned int* __restrict__ spx)
{
    const int k  = blockIdx.x * 256 + threadIdx.x;   // 16 blocks x 256 = 4096
    const int kt = k >> 4, r = k & 15;
    unsigned int hu[18], lu[18];
#pragma unroll
    for (int j = 0; j < D; ++j) {
        float res, res2;
        hu[j] = f2bf(sp[k * D + j], res);
        lu[j] = f2bf(res, res2);
    }
    unsigned int w[32];
#pragma unroll
    for (int i = 0; i < 9; ++i) {
        unsigned int hwv = hu[2 * i] | (hu[2 * i + 1] << 16);
        unsigned int lwv = lu[2 * i] | (lu[2 * i + 1] << 16);
        w[i] = hwv; w[9 + i] = hwv; w[18 + i] = lwv;
    }
#pragma unroll
    for (int i = 27; i < 32; ++i) w[i] = 0;
#pragma unroll
    for (int g = 0; g < 4; ++g) {
        unsigned int* dst = spx + (size_t)kt * 512 + (g * 16 + r) * 8;
        *(uint4*)(dst)     = make_uint4(w[g*4], w[g*4+1], w[g*4+2], w[g*4+3]);
        *(uint4*)(dst + 4) = make_uint4(w[16+g*4], w[16+g*4+1], w[16+g*4+2], w[16+g*4+3]);
    }
}

__global__ __launch_bounds__(512, 4)
void hs_main(const float* __restrict__ x, const float* __restrict__ sp,
             float* __restrict__ out_q, float* __restrict__ out_idx,
             float* __restrict__ ws_scal, const unsigned int* __restrict__ spx,
             float* __restrict__ ws_part, float* __restrict__ ws_kvec)
{
    __shared__ unsigned int xe[RPB][36];     // pixel ext rows [h|l|h|0], 144B stride
    __shared__ float        xsl_lds[RPB][20];// exact fp32 P100-scaled rows
    __shared__ float        zw[NWAVE][RPB];
    __shared__ unsigned int k1w[NWAVE][RPB], k2w[NWAVE][RPB];
    __shared__ float        An_lds[RPB];     // -(P100 + 8 + log2 Z)
    __shared__ float        entw[NWAVE];

    const int tid = threadIdx.x;
    const int l   = tid & 63;                                  // lane
    const int wu  = __builtin_amdgcn_readfirstlane(tid >> 6);  // wave id
    const int col = l & 15, g = l >> 4;
    const int kof = g * 4;
    const int row = blockIdx.x * RPB + l;
    const int b   = row >> 12;
    const int p   = row & 4095;

    // ---- wave 0: load+normalize x rows (P100-scaled); build xe + xsl ----
    if (wu == 0) {
        float xs[D];
        float ssq = 0.f;
#pragma unroll
        for (int j = 0; j < D; ++j) {
            float v = x[(b * D + j) * 4096 + p];
            xs[j] = v;
            ssq += v * v;
        }
        const float sf = (1.0f / sqrtf(ssq)) * P100;
#pragma unroll
        for (int j = 0; j < D; ++j) xs[j] *= sf;
#pragma unroll
        for (int j = 0; j < D; ++j) xsl_lds[l][j] = xs[j];

        unsigned int hu[18], lu[18];
#pragma unroll
        for (int j = 0; j < D; ++j) {
            float res, res2;
            hu[j] = f2bf(xs[j], res);
            lu[j] = f2bf(res, res2);
        }
#pragma unroll
        for (int i = 0; i < 9; ++i) {
            unsigned int hwv = hu[2 * i] | (hu[2 * i + 1] << 16);
            unsigned int lwv = lu[2 * i] | (lu[2 * i + 1] << 16);
            xe[l][i] = hwv; xe[l][9 + i] = lwv; xe[l][18 + i] = hwv;
        }
#pragma unroll
        for (int i = 27; i < 32; ++i) xe[l][i] = 0;
    }
    __syncthreads();

    // ---- loop-invariant X fragments (shared by both sweeps) ----
    union { uint4 u; bf16x8 v; } cv;
    bf16x8 fxlo[NPT], fxhi[NPT];
#pragma unroll
    for (int pt = 0; pt < NPT; ++pt) {
        cv.u = *(const uint4*)&xe[pt * 16 + col][g * 4];      fxlo[pt] = cv.v;
        cv.u = *(const uint4*)&xe[pt * 16 + col][16 + g * 4]; fxhi[pt] = cv.v;
    }

    // ---- sweep 1 (MFMA): t = P100*s - (P100+8); Z + packed top-2 keys ----
    float Zp[NPT] = {0.f, 0.f, 0.f, 0.f};
    unsigned int k1p[NPT] = {0u, 0u, 0u, 0u};
    unsigned int k2p[NPT] = {0u, 0u, 0u, 0u};
    const int kt0 = wu * KTPW;

#pragma unroll 2
    for (int kt = 0; kt < KTPW; ++kt) {
        const uint4* ap = (const uint4*)(spx + (size_t)(kt0 + kt) * 512 + l * 8);
        cv.u = ap[0]; const bf16x8 alo = cv.v;
        cv.u = ap[1]; const bf16x8 ahi = cv.v;
        const unsigned int inv0 = 4095u - (unsigned int)((kt0 + kt) * 16 + kof);
#pragma unroll
        for (int pt = 0; pt < NPT; ++pt) {
            f32x4 c = {SEED1, SEED1, SEED1, SEED1};
            c = __builtin_amdgcn_mfma_f32_16x16x32_bf16(alo, fxlo[pt], c, 0, 0, 0);
            c = __builtin_amdgcn_mfma_f32_16x16x32_bf16(ahi, fxhi[pt], c, 0, 0, 0);
#pragma unroll
            for (int r = 0; r < 4; ++r) {
                const float t = c[r];
                const unsigned int okey = ~__float_as_uint(t);
                const unsigned int key = (okey & 0xFFFFF000u) | (inv0 - (unsigned)r);
                k2p[pt] = max(k2p[pt], min(k1p[pt], key));   // uses old k1p
                k1p[pt] = max(k1p[pt], key);
                Zp[pt] += __builtin_amdgcn_exp2f(t);
            }
        }
    }

    // merge across the 4 g-groups (lanes col, col+16, col+32, col+48)
#pragma unroll
    for (int off = 16; off < 64; off <<= 1) {
#pragma unroll
        for (int pt = 0; pt < NPT; ++pt) {
            Zp[pt] += __shfl_xor(Zp[pt], off);
            unsigned int ok1 = (unsigned int)__shfl_xor((int)k1p[pt], off);
            unsigned int ok2 = (unsigned int)__shfl_xor((int)k2p[pt], off);
            k2p[pt] = max(max(k2p[pt], ok2), min(k1p[pt], ok1));
            k1p[pt] = max(k1p[pt], ok1);
        }
    }
    if (g == 0) {
#pragma unroll
        for (int pt = 0; pt < NPT; ++pt) {
            const int px = pt * 16 + col;
            zw[wu][px] = Zp[pt];
            k1w[wu][px] = k1p[pt];
            k2w[wu][px] = k2p[pt];
        }
    }
    __syncthreads();

    // ---- wave 0: cross-wave merge + recheck + epilogue ----
    if (wu == 0) {
        float Zt = zw[0][l];
        unsigned int k1 = k1w[0][l], k2 = k2w[0][l];
#pragma unroll
        for (int s = 1; s < NWAVE; ++s) {
            Zt += zw[s][l];
            unsigned int ok1 = k1w[s][l], ok2 = k2w[s][l];
            k2 = max(max(k2, ok2), min(k1, ok1));
            k1 = max(k1, ok1);
        }
        const float l2Z = log2f(Zt);
        An_lds[l] = -(P100 + 8.0f + l2Z);

        float xsl[D];
#pragma unroll
        for (int j = 0; j < D; ++j) xsl[j] = xsl_lds[l][j];

        int i1 = 4095 - (int)(k1 & 0xFFFu);
        int i2 = 4095 - (int)(k2 & 0xFFFu);
        const float tq1 = __uint_as_float(~(k1 | 0xFFFu));
        const float tq2 = __uint_as_float(~(k2 | 0xFFFu));
        int it = i1;
        if (tq1 - tq2 < DELTA) {   // exact fp32 recheck of the two candidates
            const float2* r1 = (const float2*)(sp + i1 * D);
            const float2* r2 = (const float2*)(sp + i2 * D);
            float d1 = 0.f, d2 = 0.f;
#pragma unroll
            for (int j = 0; j < 9; ++j) {
                d1 = fmaf(xsl[2 * j], r1[j].x, d1);
                d1 = fmaf(xsl[2 * j + 1], r1[j].y, d1);
                d2 = fmaf(xsl[2 * j], r2[j].x, d2);
                d2 = fmaf(xsl[2 * j + 1], r2[j].y, d2);
            }
            if (d2 > d1 || (d2 == d1 && i2 < i1)) it = i2;
        }
        out_idx[row] = (float)it;

        // gather chosen codeword (exact fp32); write q; commitment partial
        float2 gq[9];
        const float2* gr = (const float2*)(sp + it * D);
#pragma unroll
        for (int j = 0; j < 9; ++j) gq[j] = gr[j];
        float cp = 0.f;
#pragma unroll
        for (int j = 0; j < 9; ++j) {
            float qx = gq[j].x, qy = gq[j].y;
            float dx = fmaf(xsl[2 * j],     INVP100, -qx);
            float dy = fmaf(xsl[2 * j + 1], INVP100, -qy);
            cp = fmaf(dx, dx, cp);
            cp = fmaf(dy, dy, cp);
            out_q[(b * D + 2 * j)     * 4096 + p] = qx;
            out_q[(b * D + 2 * j + 1) * 4096 + p] = qy;
        }

        float v2 = cp;
#pragma unroll
        for (int off = 1; off < 64; off <<= 1) v2 += __shfl_xor(v2, off);
        if (l == 0) atomicAdd(&ws_scal[1], v2);
    }
    __syncthreads();   // publish An_lds

    // ---- sweep 2 (MFMA, roles swapped): kvec + deferred entropy ----
    // t2 = P100*s + An = log2(prob); E += e*t2 (entropy = -ln2 * E)
    float4 an4[NPT];
#pragma unroll
    for (int pt = 0; pt < NPT; ++pt)
        an4[pt] = *(const float4*)&An_lds[pt * 16 + kof];

    float entacc = 0.f;
    float* pdst = ws_part ? ws_part + (size_t)blockIdx.x * KCB : nullptr;
#pragma unroll 2
    for (int kt = 0; kt < KTPW; ++kt) {
        const uint4* ap = (const uint4*)(spx + (size_t)(kt0 + kt) * 512 + l * 8);
        cv.u = ap[0]; const bf16x8 alo = cv.v;
        cv.u = ap[1]; const bf16x8 ahi = cv.v;

        float ksum = 0.f;
#pragma unroll
        for (int pt = 0; pt < NPT; ++pt) {
            f32x4 c = {an4[pt].x, an4[pt].y, an4[pt].z, an4[pt].w};
            c = __builtin_amdgcn_mfma_f32_16x16x32_bf16(fxlo[pt], alo, c, 0, 0, 0);
            c = __builtin_amdgcn_mfma_f32_16x16x32_bf16(fxhi[pt], ahi, c, 0, 0, 0);
#pragma unroll
            for (int r = 0; r < 4; ++r) {
                const float t2 = c[r];
                const float e = __builtin_amdgcn_exp2f(t2);
                ksum += e;
                entacc = fmaf(e, t2, entacc);
            }
        }
        ksum += __shfl_xor(ksum, 16);
        ksum += __shfl_xor(ksum, 32);
        if (g == 0) {
            const int kk = (kt0 + kt) * 16 + col;
            if (pdst) pdst[kk] = ksum;
            else      atomicAdd(&ws_kvec[kk], ksum);
        }
    }

    // block-reduce deferred-entropy partials, one atomic per block
#pragma unroll
    for (int off = 1; off < 64; off <<= 1) entacc += __shfl_xor(entacc, off);
    if (l == 0) entw[wu] = entacc;
    __syncthreads();
    if (tid == 0) {
        float e = 0.f;
#pragma unroll
        for (int s = 0; s < NWAVE; ++s) e += entw[s];
        atomicAdd(&ws_scal[0], e);
    }
}

// Reduce NBLK x KCB partials into kvec (verified r5+).
__global__ void hs_reduce(const float* __restrict__ part, float* __restrict__ kvec)
{
    const int kb = blockIdx.x & 15;
    const int sb = blockIdx.x >> 4;
    const int k  = kb * 256 + threadIdx.x;
    const float* pp = part + (size_t)sb * 32 * KCB + k;
    float s = 0.f;
#pragma unroll 8
    for (int bb = 0; bb < 32; ++bb) s += pp[bb * KCB];
    atomicAdd(&kvec[k], s);
}

__global__ void hs_final(const float* __restrict__ ws_kvec,
                         const float* __restrict__ ws_scal,
                         float* __restrict__ out)
{
    __shared__ float red[4];
    const int tid = threadIdx.x;
    float local = 0.f;
    for (int k = tid; k < KCB; k += 256) {
        float a = ws_kvec[k] * (1.0f / 32768.0f);
        local += a * (log2f(a + 1e-15f) * LN2f);
    }
#pragma unroll
    for (int off = 1; off < 64; off <<= 1) local += __shfl_xor(local, off);
    if ((tid & 63) == 0) red[tid >> 6] = local;
    __syncthreads();
    if (tid == 0) {
        float mean_entro = -(red[0] + red[1] + red[2] + red[3]);
        float entro_mean = -LN2f * ws_scal[0] * (1.0f / 32768.0f);
        float commit     = ws_scal[1] * (1.0f / (32768.0f * 18.0f));
        out[SCL_OFF + 0] = entro_mean;
        out[SCL_OFF + 1] = mean_entro;
        out[SCL_OFF + 2] = entro_mean - mean_entro;
        out[SCL_OFF + 3] = commit;
    }
}

extern "C" void kernel_launch(void* const* d_in, const int* in_sizes, int n_in,
                              void* d_out, int out_size, void* d_ws, size_t ws_size,
                              hipStream_t stream)
{
    const float* x  = (const float*)d_in[0];
    const float* sp = (const float*)d_in[1];
    float* out = (float*)d_out;
    float* ws  = (float*)d_ws;

    const bool partials = ws_size >= (size_t)WS_END * sizeof(float);

    hipMemsetAsync(ws, 0, (WS_KVEC + KCB) * sizeof(float), stream);

    hs_prep<<<16, 256, 0, stream>>>(sp, (unsigned int*)(ws + WS_SPEXT));
    hs_main<<<NBLK, 512, 0, stream>>>(x, sp, out + Q_OFF, out + IDX_OFF,
                                      ws + WS_SCAL,
                                      (const unsigned int*)(ws + WS_SPEXT),
                                      partials ? ws + WS_PART : nullptr,
                                      ws + WS_KVEC);
    if (partials)
        hs_reduce<<<256, 256, 0, stream>>>(ws + WS_PART, ws + WS_KVEC);
    hs_final<<<1, 256, 0, stream>>>(ws + WS_KVEC, ws + WS_SCAL, out);
}